// Round 2
// 1105.246 us; speedup vs baseline: 1.2119x; 1.2119x over previous
//
#include <hip/hip_runtime.h>
#include <hip/hip_bf16.h>
#include <stdint.h>

#define NN      50000
#define MMN     12
#define NMROWS  600000
#define ORIGF   92
#define NBRF    41
#define AFD     64
#define GCH     128
#define KTOT    169
#define BBC     500
#define NAA     100
#define BN_EPS  1e-5f
#define GROWS   96

typedef unsigned short u16;
typedef __attribute__((ext_vector_type(8))) short bf16x8;
typedef __attribute__((ext_vector_type(4))) float f32x4;

__device__ __forceinline__ float b2f(u16 u) {
    union { uint32_t i; float f; } v; v.i = ((uint32_t)u) << 16; return v.f;
}
__device__ __forceinline__ float hi2f(uint32_t p) {
    union { uint32_t i; float f; } v; v.i = p & 0xffff0000u; return v.f;
}
__device__ __forceinline__ u16 f2b(float f) {
    __hip_bfloat16 h = __float2bfloat16(f);
    return *(u16*)&h;
}
// branchless fast softplus: max(x,0) + log(1 + exp(-|x|))
__device__ __forceinline__ float sp_f(float x) {
    return fmaxf(x, 0.f) + __logf(1.f + __expf(-fabsf(x)));
}
__device__ __forceinline__ float sigm_f(float x) {
    return __builtin_amdgcn_rcpf(1.f + __expf(-x));
}

// ---------------- output 1: atom_fea * mask (fp32) ----------------
__global__ void k_mask(const float* __restrict__ atom, const float* __restrict__ mask,
                       float* __restrict__ dout) {
    int i = blockIdx.x * blockDim.x + threadIdx.x;
    int stride = gridDim.x * blockDim.x;
    for (; i < NN * ORIGF; i += stride) {
        int k = i % ORIGF;
        dout[BBC + i] = atom[i] * mask[k];
    }
}

// ---------------- h = (atom*mask) @ emb_W^T  (bf16 out) ----------------
__global__ __launch_bounds__(256, 2) void k_emb(const float* __restrict__ atom,
                                                const float* __restrict__ mask,
                                                const float* __restrict__ embW,
                                                u16* __restrict__ h) {
    __shared__ float xs[4 * 96];
    int lane = threadIdx.x & 63;
    int w = threadIdx.x >> 6;
    float wr[ORIGF];
#pragma unroll
    for (int k = 0; k < ORIGF; ++k) wr[k] = embW[lane * ORIGF + k];
    float m1 = mask[lane];
    float m2 = (lane < ORIGF - 64) ? mask[64 + lane] : 0.f;
    for (int base = blockIdx.x * 4; base < NN; base += gridDim.x * 4) {
        int n = base + w;   // NN % 4 == 0
        xs[w * 96 + lane] = atom[(size_t)n * ORIGF + lane] * m1;
        if (lane < ORIGF - 64)
            xs[w * 96 + 64 + lane] = atom[(size_t)n * ORIGF + 64 + lane] * m2;
        __syncthreads();
        float acc = 0.f;
#pragma unroll
        for (int k4 = 0; k4 < ORIGF / 4; ++k4) {
            float4 f = *(const float4*)&xs[w * 96 + 4 * k4];
            acc += f.x * wr[4*k4] + f.y * wr[4*k4+1] + f.z * wr[4*k4+2] + f.w * wr[4*k4+3];
        }
        h[(size_t)n * AFD + lane] = f2b(acc);
        __syncthreads();
    }
}

// ------- C (bf16 pairs): (h@Wc^T | h@Wn^T) -------
// u32 word layout: C32[n*128 + lane]      = (C1[ch=lane], C1[ch=lane+64])
//                  C32[n*128 + 64 + lane] = (C2[ch=lane], C2[ch=lane+64])
__global__ __launch_bounds__(256, 2) void k_cn(const u16* __restrict__ h,
                                               const float* __restrict__ convW,
                                               uint32_t* __restrict__ C32) {
    __shared__ float xs[2 * AFD];
    int lane = threadIdx.x & 63;
    int w = threadIdx.x >> 6;
    int half = w & 1;
    int sub = w >> 1;
    int koff = half * AFD;
    float wa[AFD], wb[AFD];
#pragma unroll
    for (int k = 0; k < AFD; ++k) {
        wa[k] = convW[lane * KTOT + koff + k];
        wb[k] = convW[(lane + 64) * KTOT + koff + k];
    }
    for (int base = blockIdx.x * 2; base < NN; base += gridDim.x * 2) {
        int n = base + sub;   // NN % 2 == 0
        if (half == 0) xs[sub * AFD + lane] = b2f(h[(size_t)n * AFD + lane]);
        __syncthreads();
        float aa = 0.f, ab = 0.f;
#pragma unroll
        for (int k4 = 0; k4 < AFD / 4; ++k4) {
            float4 f = *(const float4*)&xs[sub * AFD + 4 * k4];
            aa += f.x * wa[4*k4] + f.y * wa[4*k4+1] + f.z * wa[4*k4+2] + f.w * wa[4*k4+3];
            ab += f.x * wb[4*k4] + f.y * wb[4*k4+1] + f.z * wb[4*k4+2] + f.w * wb[4*k4+3];
        }
        C32[(size_t)n * 128 + half * 64 + lane] = (uint32_t)f2b(aa) | ((uint32_t)f2b(ab) << 16);
        __syncthreads();
    }
}

// stage 96 fp32 rows of nbr_fea into fs[row*44 + k]  (Path B fallback only)
__device__ __forceinline__ void stage_nbrf(const float* nbrf, int r0, float* fs) {
    const float4* src = (const float4*)(nbrf + (size_t)r0 * NBRF);
    for (int t = threadIdx.x; t < (GROWS * NBRF) / 4; t += 256) {
        float4 f = src[t];
        float vals[4] = {f.x, f.y, f.z, f.w};
#pragma unroll
        for (int j = 0; j < 4; ++j) {
            int e = t * 4 + j;
            int row = e / NBRF;
            int k = e - row * NBRF;
            fs[row * 44 + k] = vals[j];
        }
    }
}

// ------- pass 1 (MFMA): gated tile = nbrf @ Wf^T (+bias col) + C1 + C2 -------
// Block: 96 edges x 128 ch. Wave w owns ch [w*16, w*16+16) and [+64) so one
// packed C32 u32 gather serves both halves. K=41 padded to 64 (col 41 = bias).
// D layout (HW-verified): col = lane&15, row = (lane>>4)*4 + reg.
// A/B frags loaded with the identical lane->k addressing, so any HW K-permutation
// cancels in the contraction.
template<bool STORE>
__global__ __launch_bounds__(256, 4) void k_gs3(
    const uint32_t* __restrict__ C32, const float* __restrict__ nbrf,
    const int* __restrict__ nbridx, const float* __restrict__ convW,
    const float* __restrict__ convb, float* __restrict__ stats,
    uint32_t* __restrict__ gated32)
{
    __shared__ __align__(16) u16 As[GROWS * 72];   // 96 rows x 64K, pad stride 72
    __shared__ __align__(16) u16 Ws[GCH * 72];     // 128 ch  x 64K, pad stride 72
    __shared__ int nidx[GROWS];
    const int tid = threadIdx.x;
    const int lane = tid & 63;
    const int w = tid >> 6;
    const int lr = lane & 15;
    const int lg = lane >> 4;
    const int r0 = blockIdx.x * GROWS;
    const int nbase = blockIdx.x * (GROWS / MMN);   // 8 atoms per block

    // stage A: nbr_fea rows -> bf16; col 41 = 1.0 (bias column), 42..63 = 0
    const float* src = nbrf + (size_t)r0 * NBRF;
    for (int e = tid; e < GROWS * NBRF; e += 256) {
        int row = e / NBRF, k = e - row * NBRF;
        As[row * 72 + k] = f2b(src[e]);
    }
    for (int e = tid; e < GROWS * 23; e += 256) {
        int row = e / 23, k = 41 + (e - row * 23);
        As[row * 72 + k] = (k == 41) ? (u16)0x3F80 : (u16)0;
    }
    // stage W: fea-part of convW (ch x 41) -> bf16; col 41 = bias, 42..63 = 0
    for (int e = tid; e < GCH * NBRF; e += 256) {
        int ch = e / NBRF, k = e - ch * NBRF;
        Ws[ch * 72 + k] = f2b(convW[ch * KTOT + 128 + k]);
    }
    for (int e = tid; e < GCH * 23; e += 256) {
        int ch = e / 23, k = 41 + (e - ch * 23);
        Ws[ch * 72 + k] = (k == 41) ? f2b(convb[ch]) : (u16)0;
    }
    if (tid < GROWS) nidx[tid] = nbridx[r0 + tid];
    __syncthreads();

    // B fragments (weights): within-tile col = lr; lo half ch = w*16+lr, hi = +64
    const u16* wlo = &Ws[(w * 16 + lr) * 72 + 8 * lg];
    const u16* whi = &Ws[(64 + w * 16 + lr) * 72 + 8 * lg];
    bf16x8 bl0 = *(const bf16x8*)(wlo);
    bf16x8 bl1 = *(const bf16x8*)(wlo + 32);
    bf16x8 bh0 = *(const bf16x8*)(whi);
    bf16x8 bh1 = *(const bf16x8*)(whi + 32);

    f32x4 acc[6][2];
    const f32x4 z = {0.f, 0.f, 0.f, 0.f};
#pragma unroll
    for (int mt = 0; mt < 6; ++mt) {
        const u16* ap = &As[(mt * 16 + lr) * 72 + 8 * lg];
        bf16x8 a0 = *(const bf16x8*)(ap);
        bf16x8 a1 = *(const bf16x8*)(ap + 32);
        acc[mt][0] = __builtin_amdgcn_mfma_f32_16x16x32_bf16(a1, bl1,
                     __builtin_amdgcn_mfma_f32_16x16x32_bf16(a0, bl0, z, 0, 0, 0), 0, 0, 0);
        acc[mt][1] = __builtin_amdgcn_mfma_f32_16x16x32_bf16(a1, bh1,
                     __builtin_amdgcn_mfma_f32_16x16x32_bf16(a0, bh0, z, 0, 0, 0), 0, 0, 0);
    }

    // epilogue: gather C1 (center) + C2 (neighbor), pack-store gated, stats
    const int word = w * 16 + lr;   // u32 word = (ch, ch+64)
    float slo = 0.f, qlo = 0.f, shi = 0.f, qhi = 0.f;
#pragma unroll
    for (int mt = 0; mt < 6; ++mt) {
        uint32_t p1[4], p2[4];
#pragma unroll
        for (int rg = 0; rg < 4; ++rg) {
            int row = mt * 16 + 4 * lg + rg;
            int n = nbase + row / MMN;
            int j = nidx[row];
            p1[rg] = C32[(size_t)n * 128 + word];
            p2[rg] = C32[(size_t)j * 128 + 64 + word];
        }
#pragma unroll
        for (int rg = 0; rg < 4; ++rg) {
            float glo = acc[mt][0][rg] + b2f((u16)p1[rg]) + b2f((u16)p2[rg]);
            float ghi = acc[mt][1][rg] + hi2f(p1[rg]) + hi2f(p2[rg]);
            if (STORE) {
                int row = mt * 16 + 4 * lg + rg;
                gated32[(size_t)(r0 + row) * 64 + word] =
                    (uint32_t)f2b(glo) | ((uint32_t)f2b(ghi) << 16);
            }
            slo += glo; qlo = fmaf(glo, glo, qlo);
            shi += ghi; qhi = fmaf(ghi, ghi, qhi);
        }
    }
    // lanes {lr, lr+16, lr+32, lr+48} hold the same channel -> butterfly reduce
    slo += __shfl_xor(slo, 16, 64); slo += __shfl_xor(slo, 32, 64);
    qlo += __shfl_xor(qlo, 16, 64); qlo += __shfl_xor(qlo, 32, 64);
    shi += __shfl_xor(shi, 16, 64); shi += __shfl_xor(shi, 32, 64);
    qhi += __shfl_xor(qhi, 16, 64); qhi += __shfl_xor(qhi, 32, 64);
    if (lane < 16) {
        atomicAdd(&stats[word], slo);
        atomicAdd(&stats[128 + word], qlo);
        atomicAdd(&stats[64 + word], shi);
        atomicAdd(&stats[128 + 64 + word], qhi);
    }
}

// ------- finalize BN: scale/shift from sums -------
__global__ void k_fin(float* __restrict__ stats, const float* __restrict__ gg,
                      const float* __restrict__ bb, int nch, float invcnt,
                      int sumoff, int sqoff, int scoff, int shoff) {
    int c = threadIdx.x;
    if (c < nch) {
        float mean = stats[sumoff + c] * invcnt;
        float var  = fmaxf(stats[sqoff + c] * invcnt - mean * mean, 0.f);
        float sc   = gg[c] * rsqrtf(var + BN_EPS);
        stats[scoff + c] = sc;
        stats[shoff + c] = bb[c] - mean * sc;
    }
}

// ------- pass 2 (Path A): stream packed gated words -------
__global__ __launch_bounds__(256) void k_acts(
    const uint32_t* __restrict__ gated32, float* __restrict__ stats,
    u16* __restrict__ summed)
{
    __shared__ float red[4][64][2];
    int lane = threadIdx.x & 63;
    int w = threadIdx.x >> 6;
    float sa = stats[384 + lane],      ba = stats[512 + lane];
    float sb = stats[384 + 64 + lane], bb = stats[512 + 64 + lane];
    int wave = blockIdx.x * 4 + w, nw = gridDim.x * 4;
    float s2 = 0.f, q2 = 0.f;
    for (int n = wave; n < NN; n += nw) {
        const uint32_t* gr = gated32 + (size_t)n * MMN * 64;
        float s = 0.f;
#pragma unroll
        for (int m = 0; m < MMN; ++m) {
            uint32_t p = gr[m * 64 + lane];        // (filt[lane], core[lane])
            float f1 = b2f((u16)p) * sa + ba;
            float cc = hi2f(p) * sb + bb;
            s += sigm_f(f1) * sp_f(cc);
        }
        summed[(size_t)n * AFD + lane] = f2b(s);
        s2 += s; q2 += s * s;
    }
    red[w][lane][0] = s2; red[w][lane][1] = q2;
    __syncthreads();
    if (threadIdx.x < 64) {
        int c = threadIdx.x;
        float a = 0, b = 0;
#pragma unroll
        for (int ww = 0; ww < 4; ++ww) { a += red[ww][c][0]; b += red[ww][c][1]; }
        atomicAdd(&stats[256 + c], a);
        atomicAdd(&stats[320 + c], b);
    }
}

// dual 41-wide dot against LDS row (Path B fallback)
__device__ __forceinline__ void edge_dot(const float* fr, const float* wfa,
                                         const float* wfb, float& aa, float& ab) {
#pragma unroll
    for (int k4 = 0; k4 < 10; ++k4) {
        float4 f = *(const float4*)&fr[4 * k4];
        aa += f.x * wfa[4*k4] + f.y * wfa[4*k4+1] + f.z * wfa[4*k4+2] + f.w * wfa[4*k4+3];
        ab += f.x * wfb[4*k4] + f.y * wfb[4*k4+1] + f.z * wfb[4*k4+2] + f.w * wfb[4*k4+3];
    }
    aa += fr[40] * wfa[40];
    ab += fr[40] * wfb[40];
}

// ------- pass 2 (Path B fallback): recompute gated edge-sequentially -------
__global__ __launch_bounds__(256) void k_act(
    const uint32_t* __restrict__ C32, const float* __restrict__ nbrf,
    const int* __restrict__ nbridx, const float* __restrict__ convW,
    const float* __restrict__ convb, float* __restrict__ stats,
    u16* __restrict__ summed)
{
    __shared__ float fs[GROWS * 44];
    __shared__ float red[4][64][2];
    int lane = threadIdx.x & 63;
    int w = threadIdx.x >> 6;
    int r0 = blockIdx.x * GROWS;
    stage_nbrf(nbrf, r0, fs);
    float wfa[NBRF], wfb[NBRF];
#pragma unroll
    for (int k = 0; k < NBRF; ++k) {
        wfa[k] = convW[lane * KTOT + 128 + k];
        wfb[k] = convW[(lane + 64) * KTOT + 128 + k];
    }
    float biasa = convb[lane], biasb = convb[64 + lane];
    float sa = stats[384 + lane],      ba = stats[512 + lane];
    float sb = stats[384 + 64 + lane], bb = stats[512 + 64 + lane];
    __syncthreads();
    float s2 = 0.f, q2 = 0.f;
    float s = 0.f;
    float c1a = 0.f, c1b = 0.f;
    for (int rr = 0; rr < 24; ++rr) {
        int rl = w * 24 + rr;
        int r = r0 + rl;
        if ((rr % MMN) == 0) {
            int n = r / MMN;
            uint32_t p1 = C32[(size_t)n * 128 + lane];
            c1a = b2f((u16)p1); c1b = b2f((u16)(p1 >> 16));
            s = 0.f;
        }
        int j = nbridx[r];
        uint32_t p2 = C32[(size_t)j * 128 + 64 + lane];
        float aa = c1a + b2f((u16)p2) + biasa;
        float ab = c1b + b2f((u16)(p2 >> 16)) + biasb;
        edge_dot(&fs[rl * 44], wfa, wfb, aa, ab);
        float f1 = aa * sa + ba;
        float cc = ab * sb + bb;
        s += sigm_f(f1) * sp_f(cc);
        if ((rr % MMN) == MMN - 1) {
            int n = r / MMN;
            summed[(size_t)n * AFD + lane] = f2b(s);
            s2 += s; q2 += s * s;
        }
    }
    red[w][lane][0] = s2; red[w][lane][1] = q2;
    __syncthreads();
    if (threadIdx.x < 64) {
        int c = threadIdx.x;
        float a = 0, b = 0;
#pragma unroll
        for (int ww = 0; ww < 4; ++ww) { a += red[ww][c][0]; b += red[ww][c][1]; }
        atomicAdd(&stats[256 + c], a);
        atomicAdd(&stats[320 + c], b);
    }
}

// ------- h = softplus(h + BN2(summed))  (bf16 h) -------
__global__ void k_update(u16* __restrict__ h, const u16* __restrict__ summed,
                         const float* __restrict__ stats) {
    int i = blockIdx.x * blockDim.x + threadIdx.x;
    int st = gridDim.x * blockDim.x;
    int c = threadIdx.x & 63;
    float sc = stats[640 + c], shf = stats[704 + c];
    for (; i < NN * AFD; i += st) {
        float x = b2f(h[i]) + b2f(summed[i]) * sc + shf;
        h[i] = f2b(sp_f(x));
    }
}

// ------- row-normalize + mean-pool per crystal -------
__global__ __launch_bounds__(256) void k_pool(const u16* __restrict__ h,
                                              const int* __restrict__ cry,
                                              float* __restrict__ pooled) {
    __shared__ float red[4][64];
    int lane = threadIdx.x & 63, w = threadIdx.x >> 6;
    int b = blockIdx.x;
    float acc = 0.f;
    for (int a = w; a < NAA; a += 4) {
        int idx = cry[b * NAA + a];
        float v = b2f(h[(size_t)idx * AFD + lane]);
        float s2 = v * v;
#pragma unroll
        for (int o = 32; o > 0; o >>= 1) s2 += __shfl_xor(s2, o, 64);
        acc += v / fmaxf(sqrtf(s2), 1e-12f);
    }
    red[w][lane] = acc;
    __syncthreads();
    if (threadIdx.x < 64) {
        float s = red[0][threadIdx.x] + red[1][threadIdx.x] +
                  red[2][threadIdx.x] + red[3][threadIdx.x];
        pooled[b * AFD + threadIdx.x] = s * (1.f / NAA);
    }
}

// ------- MLP head (fp32 out) -------
__global__ __launch_bounds__(64) void k_head(const float* __restrict__ pooled,
    const float* __restrict__ fc1W, const float* __restrict__ fc1b,
    const float* __restrict__ fc2W, const float* __restrict__ fc2b,
    const float* __restrict__ outW, const float* __restrict__ outb,
    float* __restrict__ props) {
    __shared__ float W1[64 * 65], W2[64 * 65], zbuf[64], pbuf[64];
    int l = threadIdx.x;
    for (int e = l; e < 64 * 64; e += 64) {
        int o = e >> 6, k = e & 63;
        W1[o * 65 + k] = fc1W[e];
        W2[o * 65 + k] = fc2W[e];
    }
    int b = blockIdx.x;
    pbuf[l] = pooled[b * AFD + l];
    __syncthreads();
    float acc = fc1b[l];
#pragma unroll
    for (int k = 0; k < 64; ++k) acc += pbuf[k] * W1[l * 65 + k];
    zbuf[l] = sp_f(acc);
    __syncthreads();
    acc = fc2b[l];
#pragma unroll
    for (int k = 0; k < 64; ++k) acc += zbuf[k] * W2[l * 65 + k];
    float v = sp_f(acc) * outW[l];
#pragma unroll
    for (int o = 32; o > 0; o >>= 1) v += __shfl_xor(v, o, 64);
    if (l == 0) props[b] = v + outb[0];
}

extern "C" void kernel_launch(void* const* d_in, const int* in_sizes, int n_in,
                              void* d_out, int out_size, void* d_ws, size_t ws_size,
                              hipStream_t stream) {
    const float* atom  = (const float*)d_in[0];
    const float* nbrf  = (const float*)d_in[1];
    const int* nbridx  = (const int*)d_in[2];
    const int* cry     = (const int*)d_in[3];
    const float* mask  = (const float*)d_in[4];
    const float* embW  = (const float*)d_in[5];
    const float* convW = (const float*)d_in[6];
    const float* convb = (const float*)d_in[7];
    const float* bn1g  = (const float*)d_in[8];
    const float* bn1b  = (const float*)d_in[9];
    const float* bn2g  = (const float*)d_in[10];
    const float* bn2b  = (const float*)d_in[11];
    const float* fc1W  = (const float*)d_in[12];
    const float* fc1b  = (const float*)d_in[13];
    const float* fc2W  = (const float*)d_in[14];
    const float* fc2b  = (const float*)d_in[15];
    const float* outW  = (const float*)d_in[16];
    const float* outb  = (const float*)d_in[17];

    char* ws = (char*)d_ws;
    float* stats    = (float*)ws;                      // 768 floats
    float* pooled   = (float*)(ws + 4096);             // 128,000 B
    u16*   h        = (u16*)(ws + (1u << 20));         // 6.4 MB
    u16*   summed   = (u16*)(ws + (8u << 20));         // 6.4 MB
    uint32_t* C32   = (uint32_t*)(ws + (16u << 20));   // 25.6 MB
    uint32_t* gated32 = (uint32_t*)(ws + (48u << 20)); // 153.6 MB (Path A only)
    const bool bigws = ws_size >= (size_t)(48u << 20) + 153600000u;

    float* out_props = (float*)d_out;

    k_mask<<<2048, 256, 0, stream>>>(atom, mask, (float*)d_out);
    k_emb<<<512, 256, 0, stream>>>(atom, mask, embW, h);
    for (int i = 0; i < 3; ++i) {
        hipMemsetAsync(stats, 0, 384 * sizeof(float), stream);
        k_cn<<<1024, 256, 0, stream>>>(h, convW + (size_t)i * GCH * KTOT, C32);
        if (bigws)
            k_gs3<true><<<NMROWS / GROWS, 256, 0, stream>>>(C32, nbrf, nbridx,
                convW + (size_t)i * GCH * KTOT, convb + (size_t)i * GCH, stats, gated32);
        else
            k_gs3<false><<<NMROWS / GROWS, 256, 0, stream>>>(C32, nbrf, nbridx,
                convW + (size_t)i * GCH * KTOT, convb + (size_t)i * GCH, stats, gated32);
        k_fin<<<1, 128, 0, stream>>>(stats, bn1g + (size_t)i * GCH, bn1b + (size_t)i * GCH,
                                     128, 1.f / NMROWS, 0, 128, 384, 512);
        if (bigws)
            k_acts<<<256, 256, 0, stream>>>(gated32, stats, summed);
        else
            k_act<<<NMROWS / GROWS, 256, 0, stream>>>(C32, nbrf, nbridx,
                convW + (size_t)i * GCH * KTOT, convb + (size_t)i * GCH, stats, summed);
        k_fin<<<1, 128, 0, stream>>>(stats, bn2g + (size_t)i * AFD, bn2b + (size_t)i * AFD,
                                     64, 1.f / NN, 256, 320, 640, 704);
        k_update<<<1024, 256, 0, stream>>>(h, summed, stats);
    }
    k_pool<<<BBC, 256, 0, stream>>>(h, cry, pooled);
    k_head<<<BBC, 64, 0, stream>>>(pooled, fc1W, fc1b, fc2W, fc2b, outW, outb, out_props);
}

// Round 3
// 1039.873 us; speedup vs baseline: 1.2880x; 1.0629x over previous
//
#include <hip/hip_runtime.h>
#include <hip/hip_bf16.h>
#include <stdint.h>

#define NN      50000
#define MMN     12
#define NMROWS  600000
#define ORIGF   92
#define NBRF    41
#define AFD     64
#define GCH     128
#define KTOT    169
#define BBC     500
#define NAA     100
#define BN_EPS  1e-5f
#define GROWS   96

typedef unsigned short u16;
typedef __attribute__((ext_vector_type(8))) short bf16x8;
typedef __attribute__((ext_vector_type(4))) float f32x4;

__device__ __forceinline__ float b2f(u16 u) {
    union { uint32_t i; float f; } v; v.i = ((uint32_t)u) << 16; return v.f;
}
__device__ __forceinline__ float hi2f(uint32_t p) {
    union { uint32_t i; float f; } v; v.i = p & 0xffff0000u; return v.f;
}
__device__ __forceinline__ u16 f2b(float f) {
    __hip_bfloat16 h = __float2bfloat16(f);
    return *(u16*)&h;
}
// branchless fast softplus: max(x,0) + log(1 + exp(-|x|))
__device__ __forceinline__ float sp_f(float x) {
    return fmaxf(x, 0.f) + __logf(1.f + __expf(-fabsf(x)));
}
__device__ __forceinline__ float sigm_f(float x) {
    return __builtin_amdgcn_rcpf(1.f + __expf(-x));
}

// ---------------- output 1: atom_fea * mask (fp32) ----------------
__global__ void k_mask(const float* __restrict__ atom, const float* __restrict__ mask,
                       float* __restrict__ dout) {
    int i = blockIdx.x * blockDim.x + threadIdx.x;
    int stride = gridDim.x * blockDim.x;
    for (; i < NN * ORIGF; i += stride) {
        int k = i % ORIGF;
        dout[BBC + i] = atom[i] * mask[k];
    }
}

// ---------------- h = (atom*mask) @ emb_W^T  (bf16 out) ----------------
__global__ __launch_bounds__(256, 2) void k_emb(const float* __restrict__ atom,
                                                const float* __restrict__ mask,
                                                const float* __restrict__ embW,
                                                u16* __restrict__ h) {
    __shared__ float xs[4 * 96];
    int lane = threadIdx.x & 63;
    int w = threadIdx.x >> 6;
    float wr[ORIGF];
#pragma unroll
    for (int k = 0; k < ORIGF; ++k) wr[k] = embW[lane * ORIGF + k];
    float m1 = mask[lane];
    float m2 = (lane < ORIGF - 64) ? mask[64 + lane] : 0.f;
    for (int base = blockIdx.x * 4; base < NN; base += gridDim.x * 4) {
        int n = base + w;   // NN % 4 == 0
        xs[w * 96 + lane] = atom[(size_t)n * ORIGF + lane] * m1;
        if (lane < ORIGF - 64)
            xs[w * 96 + 64 + lane] = atom[(size_t)n * ORIGF + 64 + lane] * m2;
        __syncthreads();
        float acc = 0.f;
#pragma unroll
        for (int k4 = 0; k4 < ORIGF / 4; ++k4) {
            float4 f = *(const float4*)&xs[w * 96 + 4 * k4];
            acc += f.x * wr[4*k4] + f.y * wr[4*k4+1] + f.z * wr[4*k4+2] + f.w * wr[4*k4+3];
        }
        h[(size_t)n * AFD + lane] = f2b(acc);
        __syncthreads();
    }
}

// ------- C (bf16 pairs): (h@Wc^T | h@Wn^T) -------
// u32 word layout: C32[n*128 + lane]      = (C1[ch=lane], C1[ch=lane+64])
//                  C32[n*128 + 64 + lane] = (C2[ch=lane], C2[ch=lane+64])
__global__ __launch_bounds__(256, 2) void k_cn(const u16* __restrict__ h,
                                               const float* __restrict__ convW,
                                               uint32_t* __restrict__ C32) {
    __shared__ float xs[2 * AFD];
    int lane = threadIdx.x & 63;
    int w = threadIdx.x >> 6;
    int half = w & 1;
    int sub = w >> 1;
    int koff = half * AFD;
    float wa[AFD], wb[AFD];
#pragma unroll
    for (int k = 0; k < AFD; ++k) {
        wa[k] = convW[lane * KTOT + koff + k];
        wb[k] = convW[(lane + 64) * KTOT + koff + k];
    }
    for (int base = blockIdx.x * 2; base < NN; base += gridDim.x * 2) {
        int n = base + sub;   // NN % 2 == 0
        if (half == 0) xs[sub * AFD + lane] = b2f(h[(size_t)n * AFD + lane]);
        __syncthreads();
        float aa = 0.f, ab = 0.f;
#pragma unroll
        for (int k4 = 0; k4 < AFD / 4; ++k4) {
            float4 f = *(const float4*)&xs[sub * AFD + 4 * k4];
            aa += f.x * wa[4*k4] + f.y * wa[4*k4+1] + f.z * wa[4*k4+2] + f.w * wa[4*k4+3];
            ab += f.x * wb[4*k4] + f.y * wb[4*k4+1] + f.z * wb[4*k4+2] + f.w * wb[4*k4+3];
        }
        C32[(size_t)n * 128 + half * 64 + lane] = (uint32_t)f2b(aa) | ((uint32_t)f2b(ab) << 16);
        __syncthreads();
    }
}

// stage 96 fp32 rows of nbr_fea into fs[row*44 + k]  (Path B fallback only)
__device__ __forceinline__ void stage_nbrf(const float* nbrf, int r0, float* fs) {
    const float4* src = (const float4*)(nbrf + (size_t)r0 * NBRF);
    for (int t = threadIdx.x; t < (GROWS * NBRF) / 4; t += 256) {
        float4 f = src[t];
        float vals[4] = {f.x, f.y, f.z, f.w};
#pragma unroll
        for (int j = 0; j < 4; ++j) {
            int e = t * 4 + j;
            int row = e / NBRF;
            int k = e - row * NBRF;
            fs[row * 44 + k] = vals[j];
        }
    }
}

// ------- pass 1 (MFMA, prefetched): gated = nbrf @ Wf^T (+bias) + C1 + C2 -------
// Block: 96 edges x 128 ch. All epilogue operands (C1 center rows, C2 neighbor
// rows) are staged COALESCED into LDS at block start so their latency hides
// under As staging + B-frag construction. W frags load directly from global
// (L2-hot) into registers with the SAME logical k-mapping as A (k=8lg+e /
// 32+8lg+e), so the MFMA contraction is exact. k=41 column carries the bias.
// D layout (HW-verified): col = lane&15, row = (lane>>4)*4 + reg.
template<bool STORE>
__global__ __launch_bounds__(256, 4) void k_gs4(
    const uint32_t* __restrict__ C32, const float* __restrict__ nbrf,
    const int* __restrict__ nbridx, const float* __restrict__ convW,
    const float* __restrict__ convb, float* __restrict__ stats,
    uint32_t* __restrict__ gated32)
{
    __shared__ __align__(16) u16 As[GROWS * 56];   // 10752 B, k=0..55 (41=bias col)
    __shared__ uint32_t C2s[GROWS * 65];           // 24960 B, stride 65 (2-way banks)
    __shared__ uint32_t C1s[8 * 65];               // 2080 B
    const int tid  = threadIdx.x;
    const int lane = tid & 63;
    const int w    = tid >> 6;
    const int lr   = lane & 15;
    const int lg   = lane >> 4;
    const int r0    = blockIdx.x * GROWS;
    const int nbase = blockIdx.x * (GROWS / MMN);   // 8 atoms per block
    const int rowb  = w * 24;                       // this wave stages rows rowb..rowb+23

    // ---- issue C2 batch 1 (12 coalesced 256B rows per wave) ----
    uint32_t c2v[12];
#pragma unroll
    for (int rr = 0; rr < 12; ++rr) {
        int j = nbridx[r0 + rowb + rr];
        c2v[rr] = C32[(size_t)j * 128 + 64 + lane];
    }
    // ---- issue C1 (8 atoms x 64 words, 2 coalesced loads/thread) ----
    uint32_t c1v[2];
#pragma unroll
    for (int q = 0; q < 2; ++q) {
        int e = tid + q * 256;
        c1v[q] = C32[(size_t)(nbase + (e >> 6)) * 128 + (e & 63)];
    }
    // ---- As staging: 96x41 nbrf -> bf16 (vectorized, coalesced) ----
    const float4* src4 = (const float4*)(nbrf + (size_t)r0 * NBRF);  // 16B aligned
#pragma unroll
    for (int it = 0; it < 4; ++it) {
        int t = tid + it * 256;
        if (it < 3 || t < 984) {          // 984 = 96*41/4
            float4 f = src4[t];
            float vals[4] = {f.x, f.y, f.z, f.w};
#pragma unroll
            for (int jj = 0; jj < 4; ++jj) {
                int e = t * 4 + jj;
                int row = e / NBRF;
                int k = e - row * NBRF;
                As[row * 56 + k] = f2b(vals[jj]);
            }
        }
    }
    // ---- write C2 batch 1, issue batch 2 ----
#pragma unroll
    for (int rr = 0; rr < 12; ++rr) C2s[(rowb + rr) * 65 + lane] = c2v[rr];
#pragma unroll
    for (int rr = 0; rr < 12; ++rr) {
        int j = nbridx[r0 + rowb + 12 + rr];
        c2v[rr] = C32[(size_t)j * 128 + 64 + lane];
    }
#pragma unroll
    for (int q = 0; q < 2; ++q) {
        int e = tid + q * 256;
        C1s[(e >> 6) * 65 + (e & 63)] = c1v[q];
    }
    // ---- As pad: k=41 -> 1.0 (bias column), 42..55 -> 0 ----
#pragma unroll
    for (int it = 0; it < 6; ++it) {
        int e = tid + it * 256;
        if (it < 5 || e < 1440) {         // 1440 = 96*15
            int row = e / 15;
            int k = 41 + (e - row * 15);
            As[row * 56 + k] = (k == 41) ? (u16)0x3F80 : (u16)0;
        }
    }
    // ---- B frags direct from global (L2-hot), same k-mapping as A ----
    const int chlo = w * 16 + lr;
    const int chhi = chlo + 64;
    const float* wlo = convW + (size_t)chlo * KTOT + 128;
    const float* whi = convW + (size_t)chhi * KTOT + 128;
    bf16x8 bl0, bh0;
    bf16x8 bl1 = {0,0,0,0,0,0,0,0}, bh1 = {0,0,0,0,0,0,0,0};
#pragma unroll
    for (int e = 0; e < 8; ++e) {
        bl0[e] = (short)f2b(wlo[8 * lg + e]);
        bh0[e] = (short)f2b(whi[8 * lg + e]);
    }
    if (lg == 0) {
#pragma unroll
        for (int e = 0; e < 8; ++e) {
            bl1[e] = (short)f2b(wlo[32 + e]);
            bh1[e] = (short)f2b(whi[32 + e]);
        }
    } else if (lg == 1) {
        bl1[0] = (short)f2b(wlo[40]); bl1[1] = (short)f2b(convb[chlo]);
        bh1[0] = (short)f2b(whi[40]); bh1[1] = (short)f2b(convb[chhi]);
    }
    // ---- write C2 batch 2 ----
#pragma unroll
    for (int rr = 0; rr < 12; ++rr) C2s[(rowb + 12 + rr) * 65 + lane] = c2v[rr];
    __syncthreads();

    // ---- MFMA: 6 M-tiles x 2 channel halves ----
    f32x4 acc[6][2];
    const f32x4 z = {0.f, 0.f, 0.f, 0.f};
    const bf16x8 zb = {0,0,0,0,0,0,0,0};
#pragma unroll
    for (int mt = 0; mt < 6; ++mt) {
        const u16* ap = &As[(mt * 16 + lr) * 56 + 8 * lg];
        bf16x8 a0 = *(const bf16x8*)ap;
        bf16x8 a1 = zb;
        if (lg < 3) a1 = *(const bf16x8*)(ap + 32);   // k=32+8lg..39+8lg (<56)
        acc[mt][0] = __builtin_amdgcn_mfma_f32_16x16x32_bf16(a1, bl1,
                     __builtin_amdgcn_mfma_f32_16x16x32_bf16(a0, bl0, z, 0, 0, 0), 0, 0, 0);
        acc[mt][1] = __builtin_amdgcn_mfma_f32_16x16x32_bf16(a1, bh1,
                     __builtin_amdgcn_mfma_f32_16x16x32_bf16(a0, bh0, z, 0, 0, 0), 0, 0, 0);
    }

    // ---- epilogue: all operands in LDS; combine, store, stats ----
    const int word = w * 16 + lr;   // u32 word = (ch, ch+64)
    float slo = 0.f, qlo = 0.f, shi = 0.f, qhi = 0.f;
#pragma unroll
    for (int mt = 0; mt < 6; ++mt) {
#pragma unroll
        for (int rg = 0; rg < 4; ++rg) {
            int row = mt * 16 + 4 * lg + rg;
            uint32_t p1 = C1s[(row / MMN) * 65 + word];
            uint32_t p2 = C2s[row * 65 + word];
            float glo = acc[mt][0][rg] + b2f((u16)p1) + b2f((u16)p2);
            float ghi = acc[mt][1][rg] + hi2f(p1) + hi2f(p2);
            if (STORE) {
                gated32[(size_t)(r0 + row) * 64 + word] =
                    (uint32_t)f2b(glo) | ((uint32_t)f2b(ghi) << 16);
            }
            slo += glo; qlo = fmaf(glo, glo, qlo);
            shi += ghi; qhi = fmaf(ghi, ghi, qhi);
        }
    }
    // lanes {lr, lr+16, lr+32, lr+48} hold the same channel -> butterfly reduce
    slo += __shfl_xor(slo, 16, 64); slo += __shfl_xor(slo, 32, 64);
    qlo += __shfl_xor(qlo, 16, 64); qlo += __shfl_xor(qlo, 32, 64);
    shi += __shfl_xor(shi, 16, 64); shi += __shfl_xor(shi, 32, 64);
    qhi += __shfl_xor(qhi, 16, 64); qhi += __shfl_xor(qhi, 32, 64);
    if (lane < 16) {
        atomicAdd(&stats[word], slo);
        atomicAdd(&stats[128 + word], qlo);
        atomicAdd(&stats[64 + word], shi);
        atomicAdd(&stats[128 + 64 + word], qhi);
    }
}

// ------- finalize BN: scale/shift from sums -------
__global__ void k_fin(float* __restrict__ stats, const float* __restrict__ gg,
                      const float* __restrict__ bb, int nch, float invcnt,
                      int sumoff, int sqoff, int scoff, int shoff) {
    int c = threadIdx.x;
    if (c < nch) {
        float mean = stats[sumoff + c] * invcnt;
        float var  = fmaxf(stats[sqoff + c] * invcnt - mean * mean, 0.f);
        float sc   = gg[c] * rsqrtf(var + BN_EPS);
        stats[scoff + c] = sc;
        stats[shoff + c] = bb[c] - mean * sc;
    }
}

// ------- pass 2 (Path A): stream packed gated words -------
__global__ __launch_bounds__(256) void k_acts(
    const uint32_t* __restrict__ gated32, float* __restrict__ stats,
    u16* __restrict__ summed)
{
    __shared__ float red[4][64][2];
    int lane = threadIdx.x & 63;
    int w = threadIdx.x >> 6;
    float sa = stats[384 + lane],      ba = stats[512 + lane];
    float sb = stats[384 + 64 + lane], bb = stats[512 + 64 + lane];
    int wave = blockIdx.x * 4 + w, nw = gridDim.x * 4;
    float s2 = 0.f, q2 = 0.f;
    for (int n = wave; n < NN; n += nw) {
        const uint32_t* gr = gated32 + (size_t)n * MMN * 64;
        float s = 0.f;
#pragma unroll
        for (int m = 0; m < MMN; ++m) {
            uint32_t p = gr[m * 64 + lane];        // (filt[lane], core[lane])
            float f1 = b2f((u16)p) * sa + ba;
            float cc = hi2f(p) * sb + bb;
            s += sigm_f(f1) * sp_f(cc);
        }
        summed[(size_t)n * AFD + lane] = f2b(s);
        s2 += s; q2 += s * s;
    }
    red[w][lane][0] = s2; red[w][lane][1] = q2;
    __syncthreads();
    if (threadIdx.x < 64) {
        int c = threadIdx.x;
        float a = 0, b = 0;
#pragma unroll
        for (int ww = 0; ww < 4; ++ww) { a += red[ww][c][0]; b += red[ww][c][1]; }
        atomicAdd(&stats[256 + c], a);
        atomicAdd(&stats[320 + c], b);
    }
}

// dual 41-wide dot against LDS row (Path B fallback)
__device__ __forceinline__ void edge_dot(const float* fr, const float* wfa,
                                         const float* wfb, float& aa, float& ab) {
#pragma unroll
    for (int k4 = 0; k4 < 10; ++k4) {
        float4 f = *(const float4*)&fr[4 * k4];
        aa += f.x * wfa[4*k4] + f.y * wfa[4*k4+1] + f.z * wfa[4*k4+2] + f.w * wfa[4*k4+3];
        ab += f.x * wfb[4*k4] + f.y * wfb[4*k4+1] + f.z * wfb[4*k4+2] + f.w * wfb[4*k4+3];
    }
    aa += fr[40] * wfa[40];
    ab += fr[40] * wfb[40];
}

// ------- pass 2 (Path B fallback): recompute gated edge-sequentially -------
__global__ __launch_bounds__(256) void k_act(
    const uint32_t* __restrict__ C32, const float* __restrict__ nbrf,
    const int* __restrict__ nbridx, const float* __restrict__ convW,
    const float* __restrict__ convb, float* __restrict__ stats,
    u16* __restrict__ summed)
{
    __shared__ float fs[GROWS * 44];
    __shared__ float red[4][64][2];
    int lane = threadIdx.x & 63;
    int w = threadIdx.x >> 6;
    int r0 = blockIdx.x * GROWS;
    stage_nbrf(nbrf, r0, fs);
    float wfa[NBRF], wfb[NBRF];
#pragma unroll
    for (int k = 0; k < NBRF; ++k) {
        wfa[k] = convW[lane * KTOT + 128 + k];
        wfb[k] = convW[(lane + 64) * KTOT + 128 + k];
    }
    float biasa = convb[lane], biasb = convb[64 + lane];
    float sa = stats[384 + lane],      ba = stats[512 + lane];
    float sb = stats[384 + 64 + lane], bb = stats[512 + 64 + lane];
    __syncthreads();
    float s2 = 0.f, q2 = 0.f;
    float s = 0.f;
    float c1a = 0.f, c1b = 0.f;
    for (int rr = 0; rr < 24; ++rr) {
        int rl = w * 24 + rr;
        int r = r0 + rl;
        if ((rr % MMN) == 0) {
            int n = r / MMN;
            uint32_t p1 = C32[(size_t)n * 128 + lane];
            c1a = b2f((u16)p1); c1b = b2f((u16)(p1 >> 16));
            s = 0.f;
        }
        int j = nbridx[r];
        uint32_t p2 = C32[(size_t)j * 128 + 64 + lane];
        float aa = c1a + b2f((u16)p2) + biasa;
        float ab = c1b + b2f((u16)(p2 >> 16)) + biasb;
        edge_dot(&fs[rl * 44], wfa, wfb, aa, ab);
        float f1 = aa * sa + ba;
        float cc = ab * sb + bb;
        s += sigm_f(f1) * sp_f(cc);
        if ((rr % MMN) == MMN - 1) {
            int n = r / MMN;
            summed[(size_t)n * AFD + lane] = f2b(s);
            s2 += s; q2 += s * s;
        }
    }
    red[w][lane][0] = s2; red[w][lane][1] = q2;
    __syncthreads();
    if (threadIdx.x < 64) {
        int c = threadIdx.x;
        float a = 0, b = 0;
#pragma unroll
        for (int ww = 0; ww < 4; ++ww) { a += red[ww][c][0]; b += red[ww][c][1]; }
        atomicAdd(&stats[256 + c], a);
        atomicAdd(&stats[320 + c], b);
    }
}

// ------- h = softplus(h + BN2(summed))  (bf16 h) -------
__global__ void k_update(u16* __restrict__ h, const u16* __restrict__ summed,
                         const float* __restrict__ stats) {
    int i = blockIdx.x * blockDim.x + threadIdx.x;
    int st = gridDim.x * blockDim.x;
    int c = threadIdx.x & 63;
    float sc = stats[640 + c], shf = stats[704 + c];
    for (; i < NN * AFD; i += st) {
        float x = b2f(h[i]) + b2f(summed[i]) * sc + shf;
        h[i] = f2b(sp_f(x));
    }
}

// ------- row-normalize + mean-pool per crystal -------
__global__ __launch_bounds__(256) void k_pool(const u16* __restrict__ h,
                                              const int* __restrict__ cry,
                                              float* __restrict__ pooled) {
    __shared__ float red[4][64];
    int lane = threadIdx.x & 63, w = threadIdx.x >> 6;
    int b = blockIdx.x;
    float acc = 0.f;
    for (int a = w; a < NAA; a += 4) {
        int idx = cry[b * NAA + a];
        float v = b2f(h[(size_t)idx * AFD + lane]);
        float s2 = v * v;
#pragma unroll
        for (int o = 32; o > 0; o >>= 1) s2 += __shfl_xor(s2, o, 64);
        acc += v / fmaxf(sqrtf(s2), 1e-12f);
    }
    red[w][lane] = acc;
    __syncthreads();
    if (threadIdx.x < 64) {
        float s = red[0][threadIdx.x] + red[1][threadIdx.x] +
                  red[2][threadIdx.x] + red[3][threadIdx.x];
        pooled[b * AFD + threadIdx.x] = s * (1.f / NAA);
    }
}

// ------- MLP head (fp32 out) -------
__global__ __launch_bounds__(64) void k_head(const float* __restrict__ pooled,
    const float* __restrict__ fc1W, const float* __restrict__ fc1b,
    const float* __restrict__ fc2W, const float* __restrict__ fc2b,
    const float* __restrict__ outW, const float* __restrict__ outb,
    float* __restrict__ props) {
    __shared__ float W1[64 * 65], W2[64 * 65], zbuf[64], pbuf[64];
    int l = threadIdx.x;
    for (int e = l; e < 64 * 64; e += 64) {
        int o = e >> 6, k = e & 63;
        W1[o * 65 + k] = fc1W[e];
        W2[o * 65 + k] = fc2W[e];
    }
    int b = blockIdx.x;
    pbuf[l] = pooled[b * AFD + l];
    __syncthreads();
    float acc = fc1b[l];
#pragma unroll
    for (int k = 0; k < 64; ++k) acc += pbuf[k] * W1[l * 65 + k];
    zbuf[l] = sp_f(acc);
    __syncthreads();
    acc = fc2b[l];
#pragma unroll
    for (int k = 0; k < 64; ++k) acc += zbuf[k] * W2[l * 65 + k];
    float v = sp_f(acc) * outW[l];
#pragma unroll
    for (int o = 32; o > 0; o >>= 1) v += __shfl_xor(v, o, 64);
    if (l == 0) props[b] = v + outb[0];
}

extern "C" void kernel_launch(void* const* d_in, const int* in_sizes, int n_in,
                              void* d_out, int out_size, void* d_ws, size_t ws_size,
                              hipStream_t stream) {
    const float* atom  = (const float*)d_in[0];
    const float* nbrf  = (const float*)d_in[1];
    const int* nbridx  = (const int*)d_in[2];
    const int* cry     = (const int*)d_in[3];
    const float* mask  = (const float*)d_in[4];
    const float* embW  = (const float*)d_in[5];
    const float* convW = (const float*)d_in[6];
    const float* convb = (const float*)d_in[7];
    const float* bn1g  = (const float*)d_in[8];
    const float* bn1b  = (const float*)d_in[9];
    const float* bn2g  = (const float*)d_in[10];
    const float* bn2b  = (const float*)d_in[11];
    const float* fc1W  = (const float*)d_in[12];
    const float* fc1b  = (const float*)d_in[13];
    const float* fc2W  = (const float*)d_in[14];
    const float* fc2b  = (const float*)d_in[15];
    const float* outW  = (const float*)d_in[16];
    const float* outb  = (const float*)d_in[17];

    char* ws = (char*)d_ws;
    float* stats    = (float*)ws;                      // 768 floats
    float* pooled   = (float*)(ws + 4096);             // 128,000 B
    u16*   h        = (u16*)(ws + (1u << 20));         // 6.4 MB
    u16*   summed   = (u16*)(ws + (8u << 20));         // 6.4 MB
    uint32_t* C32   = (uint32_t*)(ws + (16u << 20));   // 25.6 MB
    uint32_t* gated32 = (uint32_t*)(ws + (48u << 20)); // 153.6 MB (Path A only)
    const bool bigws = ws_size >= (size_t)(48u << 20) + 153600000u;

    float* out_props = (float*)d_out;

    k_mask<<<2048, 256, 0, stream>>>(atom, mask, (float*)d_out);
    k_emb<<<512, 256, 0, stream>>>(atom, mask, embW, h);
    for (int i = 0; i < 3; ++i) {
        hipMemsetAsync(stats, 0, 384 * sizeof(float), stream);
        k_cn<<<1024, 256, 0, stream>>>(h, convW + (size_t)i * GCH * KTOT, C32);
        if (bigws)
            k_gs4<true><<<NMROWS / GROWS, 256, 0, stream>>>(C32, nbrf, nbridx,
                convW + (size_t)i * GCH * KTOT, convb + (size_t)i * GCH, stats, gated32);
        else
            k_gs4<false><<<NMROWS / GROWS, 256, 0, stream>>>(C32, nbrf, nbridx,
                convW + (size_t)i * GCH * KTOT, convb + (size_t)i * GCH, stats, gated32);
        k_fin<<<1, 128, 0, stream>>>(stats, bn1g + (size_t)i * GCH, bn1b + (size_t)i * GCH,
                                     128, 1.f / NMROWS, 0, 128, 384, 512);
        if (bigws)
            k_acts<<<1024, 256, 0, stream>>>(gated32, stats, summed);
        else
            k_act<<<NMROWS / GROWS, 256, 0, stream>>>(C32, nbrf, nbridx,
                convW + (size_t)i * GCH * KTOT, convb + (size_t)i * GCH, stats, summed);
        k_fin<<<1, 128, 0, stream>>>(stats, bn2g + (size_t)i * AFD, bn2b + (size_t)i * AFD,
                                     64, 1.f / NN, 256, 320, 640, 704);
        k_update<<<1024, 256, 0, stream>>>(h, summed, stats);
    }
    k_pool<<<BBC, 256, 0, stream>>>(h, cry, pooled);
    k_head<<<BBC, 64, 0, stream>>>(pooled, fc1W, fc1b, fc2W, fc2b, outW, outb, out_props);
}